// Round 1
// baseline (188.888 us; speedup 1.0000x reference)
//
#include <hip/hip_runtime.h>
#include <hip/hip_bf16.h>
#include <math.h>

#define NK 256          // number of kernels
#define LPAD 249        // dense kernel length
#define MAXTAPS 11      // max nonzero taps per kernel
#define TLEN 2000       // time length
#define PAD 124         // (LPAD-1)/2
#define TPADDED (TLEN + 2 * PAD)   // 2248
#define KPB 64          // kernels per block
#define THREADS 256
#define BC 256          // B*C rows

// ---- prep: extract sparse taps from dense (256,249) weight matrix ----
__global__ void extract_taps(const float* __restrict__ W,
                             int* __restrict__ offs,
                             float* __restrict__ wgt) {
    int k = blockIdx.x * blockDim.x + threadIdx.x;
    if (k >= NK) return;
    int n = 0;
    for (int l = 0; l < LPAD; ++l) {
        float w = W[k * LPAD + l];
        if (w != 0.0f) {
            if (n < MAXTAPS) {
                offs[k * MAXTAPS + n] = l;
                wgt[k * MAXTAPS + n] = w;
            }
            ++n;
        }
    }
    for (; n < MAXTAPS; ++n) {
        offs[k * MAXTAPS + n] = 0;
        wgt[k * MAXTAPS + n] = 0.0f;
    }
}

// ---- main: sparse conv + ppv/max pooling ----
__global__ __launch_bounds__(THREADS) void rocket_main(
    const float* __restrict__ x,
    const float* __restrict__ bias,
    const int* __restrict__ offs,
    const float* __restrict__ wgt,
    float* __restrict__ out) {
    __shared__ float xs[TPADDED];
    __shared__ int   s_off[KPB * MAXTAPS];
    __shared__ float s_w[KPB * MAXTAPS];
    __shared__ float s_b[KPB];

    const int bc    = blockIdx.x;      // 0..255  (b*32+c)
    const int kg    = blockIdx.y;      // 0..3
    const int kbase = kg * KPB;
    const int tid   = threadIdx.x;

    // stage padded x row (zeros in the halo)
    for (int i = tid; i < TPADDED; i += THREADS) {
        int t = i - PAD;
        xs[i] = (t >= 0 && t < TLEN) ? x[bc * TLEN + t] : 0.0f;
    }
    // stage this block's tap tables
    for (int i = tid; i < KPB * MAXTAPS; i += THREADS) {
        s_off[i] = offs[kbase * MAXTAPS + i];
        s_w[i]   = wgt[kbase * MAXTAPS + i];
    }
    if (tid < KPB) s_b[tid] = bias[kbase + tid];
    __syncthreads();

    const int wid  = tid >> 6;
    const int lane = tid & 63;

    // each wave owns 16 consecutive kernels
    for (int kk = wid * 16; kk < wid * 16 + 16; ++kk) {
        const float b = s_b[kk];
        int   o[MAXTAPS];
        float w[MAXTAPS];
#pragma unroll
        for (int j = 0; j < MAXTAPS; ++j) {
            o[j] = s_off[kk * MAXTAPS + j];
            w[j] = s_w[kk * MAXTAPS + j];
        }

        int   cnt = 0;
        float mx  = -INFINITY;
        for (int t = lane; t < TLEN; t += 64) {
            float y = b;
#pragma unroll
            for (int j = 0; j < MAXTAPS; ++j) {
                y += w[j] * xs[t + o[j]];
            }
            cnt += (y > 0.0f) ? 1 : 0;
            mx = fmaxf(mx, y);
        }

        float fc = (float)cnt;
#pragma unroll
        for (int s = 32; s; s >>= 1) {
            fc += __shfl_xor(fc, s, 64);
            mx  = fmaxf(mx, __shfl_xor(mx, s, 64));
        }
        if (lane == 0) {
            const int k = kbase + kk;
            out[bc * (2 * NK) + 2 * k]     = fc * (1.0f / (float)TLEN);
            out[bc * (2 * NK) + 2 * k + 1] = mx;
        }
    }
}

extern "C" void kernel_launch(void* const* d_in, const int* in_sizes, int n_in,
                              void* d_out, int out_size, void* d_ws, size_t ws_size,
                              hipStream_t stream) {
    const float* x    = (const float*)d_in[0];   // (8,32,2000)
    const float* W    = (const float*)d_in[1];   // (256,249)
    const float* bias = (const float*)d_in[2];   // (256,)
    float* out = (float*)d_out;                  // (8,32,512)

    // workspace layout: [int offs[256*11]][float wgt[256*11]]
    int*   offs = (int*)d_ws;
    float* wgt  = (float*)((char*)d_ws + NK * MAXTAPS * sizeof(int));

    extract_taps<<<1, 256, 0, stream>>>(W, offs, wgt);

    dim3 grid(BC, NK / KPB);  // 256 x 4
    rocket_main<<<grid, THREADS, 0, stream>>>(x, bias, offs, wgt, out);
}

// Round 2
// 138.885 us; speedup vs baseline: 1.3600x; 1.3600x over previous
//
#include <hip/hip_runtime.h>
#include <hip/hip_bf16.h>
#include <math.h>

typedef float f32x2 __attribute__((ext_vector_type(2)));

#define NK 256          // number of kernels
#define LPAD 249        // dense kernel length
#define MAXTAPS 11      // max nonzero taps per kernel
#define TLEN 2000       // time length
#define PAD 124         // (LPAD-1)/2
#define XS_LEN 2296     // t index 0..2047 plus max tap offset 248
#define KPB 32          // kernels per block
#define THREADS 256
#define BC 256          // B*C rows
#define NBLK 4          // t-blocks of 512 (64 lanes x 8 accumulators)

// ---- prep: extract sparse taps from dense (256,249) weight matrix ----
__global__ void extract_taps(const float* __restrict__ W,
                             int* __restrict__ offs,
                             float* __restrict__ wgt) {
    int k = blockIdx.x * blockDim.x + threadIdx.x;
    if (k >= NK) return;
    int n = 0;
    for (int l = 0; l < LPAD; ++l) {
        float w = W[k * LPAD + l];
        if (w != 0.0f) {
            if (n < MAXTAPS) {
                offs[k * MAXTAPS + n] = l;
                wgt[k * MAXTAPS + n] = w;
            }
            ++n;
        }
    }
    for (; n < MAXTAPS; ++n) {
        offs[k * MAXTAPS + n] = 0;
        wgt[k * MAXTAPS + n] = 0.0f;
    }
}

// ---- main: sparse conv + ppv/max pooling ----
__global__ __launch_bounds__(THREADS) void rocket_main(
    const float* __restrict__ x,
    const float* __restrict__ bias,
    const int* __restrict__ offs,
    const float* __restrict__ wgt,
    float* __restrict__ out) {
    __shared__ float xs[XS_LEN];
    __shared__ int   s_o[KPB * MAXTAPS];
    __shared__ float s_w[KPB * MAXTAPS];
    __shared__ float s_b[KPB];

    const int bc    = blockIdx.x;          // 0..255
    const int kbase = blockIdx.y * KPB;    // 0..224
    const int tid   = threadIdx.x;

    // stage padded x row (zeros outside [PAD, PAD+TLEN))
    for (int i = tid; i < XS_LEN; i += THREADS) {
        int t = i - PAD;
        xs[i] = (t >= 0 && t < TLEN) ? x[bc * TLEN + t] : 0.0f;
    }
    for (int i = tid; i < KPB * MAXTAPS; i += THREADS) {
        s_o[i] = offs[kbase * MAXTAPS + i];
        s_w[i] = wgt[kbase * MAXTAPS + i];
    }
    if (tid < KPB) s_b[tid] = bias[kbase + tid];
    __syncthreads();

    const int wid  = tid >> 6;
    const int lane = tid & 63;

    // each wave owns KPB/4 = 8 consecutive kernels
    for (int kk = wid * (KPB / 4); kk < (wid + 1) * (KPB / 4); ++kk) {
        int   o[MAXTAPS];
        f32x2 w2[MAXTAPS];
#pragma unroll
        for (int j = 0; j < MAXTAPS; ++j) {
            o[j] = s_o[kk * MAXTAPS + j];
            float w = s_w[kk * MAXTAPS + j];
            w2[j] = (f32x2){w, w};
        }
        const float b = s_b[kk];
        const f32x2 bb = (f32x2){b, b};

        int   cnt = 0;
        f32x2 mx2 = (f32x2){-INFINITY, -INFINITY};

#pragma unroll
        for (int blk = 0; blk < NBLK; ++blk) {
            const int tb = blk * 512 + lane;
            f32x2 a0 = bb, a1 = bb, a2 = bb, a3 = bb;
#pragma unroll
            for (int j = 0; j < MAXTAPS; ++j) {
                const float* p = &xs[tb + o[j]];   // one VGPR addr; 8 reads via imm offsets
                f32x2 v0 = {p[0],   p[64]};
                f32x2 v1 = {p[128], p[192]};
                f32x2 v2 = {p[256], p[320]};
                f32x2 v3 = {p[384], p[448]};
                a0 = __builtin_elementwise_fma(w2[j], v0, a0);
                a1 = __builtin_elementwise_fma(w2[j], v1, a1);
                a2 = __builtin_elementwise_fma(w2[j], v2, a2);
                a3 = __builtin_elementwise_fma(w2[j], v3, a3);
            }
            // PPV count: wave-uniform scalar via ballot + popcount (SALU pipe)
            cnt += __popcll(__ballot(a0.x > 0.0f));
            cnt += __popcll(__ballot(a0.y > 0.0f));
            cnt += __popcll(__ballot(a1.x > 0.0f));
            cnt += __popcll(__ballot(a1.y > 0.0f));
            cnt += __popcll(__ballot(a2.x > 0.0f));
            cnt += __popcll(__ballot(a2.y > 0.0f));
            cnt += __popcll(__ballot(a3.x > 0.0f));
            if (blk == NBLK - 1) {
                // a3.y covers t = 1984 + lane: only lanes 0..15 are valid
                cnt += __popcll(__ballot(a3.y > 0.0f) & 0xFFFFull);
                a3.y = (lane < 16) ? a3.y : -INFINITY;
            } else {
                cnt += __popcll(__ballot(a3.y > 0.0f));
            }
            f32x2 m01 = __builtin_elementwise_max(a0, a1);
            f32x2 m23 = __builtin_elementwise_max(a2, a3);
            mx2 = __builtin_elementwise_max(mx2, __builtin_elementwise_max(m01, m23));
        }

        float mx = fmaxf(mx2.x, mx2.y);
#pragma unroll
        for (int s = 32; s; s >>= 1) {
            mx = fmaxf(mx, __shfl_xor(mx, s, 64));
        }
        if (lane == 0) {
            const int k = kbase + kk;
            out[bc * (2 * NK) + 2 * k]     = (float)cnt * (1.0f / (float)TLEN);
            out[bc * (2 * NK) + 2 * k + 1] = mx;
        }
    }
}

extern "C" void kernel_launch(void* const* d_in, const int* in_sizes, int n_in,
                              void* d_out, int out_size, void* d_ws, size_t ws_size,
                              hipStream_t stream) {
    const float* x    = (const float*)d_in[0];   // (8,32,2000)
    const float* W    = (const float*)d_in[1];   // (256,249)
    const float* bias = (const float*)d_in[2];   // (256,)
    float* out = (float*)d_out;                  // (8,32,512)

    int*   offs = (int*)d_ws;
    float* wgt  = (float*)((char*)d_ws + NK * MAXTAPS * sizeof(int));

    extract_taps<<<1, 256, 0, stream>>>(W, offs, wgt);

    dim3 grid(BC, NK / KPB);  // 256 x 8
    rocket_main<<<grid, THREADS, 0, stream>>>(x, bias, offs, wgt, out);
}